// Round 8
// baseline (306.537 us; speedup 1.0000x reference)
//
#include <hip/hip_runtime.h>

// ---------------- problem constants ----------------
#define NTOK   32768
#define DIM    512            // bytes per fp8 row too
#define NCODE  4096
#define NELEM  (NTOK*DIM)     // 16777216
#define COMMIT 0.25
#define ESCALE 8192.0f        // 2^13: lifts emb (~2.4e-4) into e4m3 normal range
#define EINV   (1.0f/4096.0f) // 2^-12: score = en - 2*(acc/8192) = en - acc*2^-12
#define KSCL   262144.0f      // 2^18 key quantizer
#define KOFF   65536.0f       // 0.25 * 2^18 (covers |s| <= 0.25 hard bound)
// EINV*KSCL = 64: key = fmaf(en,KSCL,KOFF) - 64*acc (same ordering, fewer ops)

// ---------------- ws layout (bytes) ----------------
#define OFF_Z8      0ULL              // fp8 z: 16777216
#define OFF_E8      16777216ULL       // fp8 e*8192: 2097152
#define OFF_EN32    18874368ULL       // float[4096] = 16384
#define OFF_ROWMIN  18890752ULL       // u32[32768] = 131072 (packed key20|code12)
#define OFF_COUNTS  19021824ULL       // u32[4096] = 16384
#define OFF_SSE     19038208ULL       // double[256] = 2048

typedef int   v8i  __attribute__((ext_vector_type(8)));
typedef float v16f __attribute__((ext_vector_type(16)));

#define GLOBAL_AS __attribute__((address_space(1)))
#define LDS_AS    __attribute__((address_space(3)))

__device__ __forceinline__ void gld16(const void* g, void* l) {
    // async global->LDS, 16B/lane; LDS dest = wave-uniform base + lane*16
    __builtin_amdgcn_global_load_lds((const GLOBAL_AS unsigned int*)g,
                                     (LDS_AS unsigned int*)l, 16, 0, 0);
}

// ---------------- 1. fp32 -> fp8 e4m3 conversion (+ counts/sse init) ----------
__global__ void conv_kernel(const float* __restrict__ z, const float* __restrict__ e,
                            unsigned* __restrict__ z8, unsigned* __restrict__ e8,
                            unsigned* __restrict__ counts, double* __restrict__ sse) {
    const int ZI = NELEM / 16;                 // 1048576 (16 floats -> 16 fp8 per thread)
    const int TI = ZI + (NCODE * DIM) / 16;    // +131072
    int i = blockIdx.x * blockDim.x + threadIdx.x;
    if (i < NCODE) counts[i] = 0u;
    if (i < 256)   sse[i] = 0.0;
    if (i >= TI) return;
    const float4* src; unsigned* dst; int j; float sc;
    if (i < ZI) { src = (const float4*)z; dst = z8; j = i; sc = 1.0f; }
    else        { src = (const float4*)e; dst = e8; j = i - ZI; sc = ESCALE; }
    uint4 o;
#pragma unroll
    for (int q = 0; q < 4; q++) {
        float4 v = src[j * 4 + q];
        int r = 0;
        r = __builtin_amdgcn_cvt_pk_fp8_f32(v.x * sc, v.y * sc, r, false);
        r = __builtin_amdgcn_cvt_pk_fp8_f32(v.z * sc, v.w * sc, r, true);
        (&o.x)[q] = (unsigned)r;
    }
    ((uint4*)dst)[j] = o;
}

// ---------------- 2. ||e_k||^2 (exact f32 via f64 accumulate) ----------------
__global__ void enorm_kernel(const float* __restrict__ emb, float* __restrict__ en32) {
    int gw = (blockIdx.x * blockDim.x + threadIdx.x) >> 6;   // wave id = code
    int lane = threadIdx.x & 63;
    if (gw >= NCODE) return;
    const float4* p = (const float4*)(emb + (size_t)gw * DIM);
    float4 a = p[lane * 2], b = p[lane * 2 + 1];
    double s = (double)a.x*a.x + (double)a.y*a.y + (double)a.z*a.z + (double)a.w*a.w
             + (double)b.x*b.x + (double)b.y*b.y + (double)b.z*b.z + (double)b.w*b.w;
    for (int off = 32; off; off >>= 1) s += __shfl_down(s, off);
    if (lane == 0) en32[gw] = (float)s;
}

// ---------------- 3. persistent-code-loop MX-fp8 score pass (v7) -----------
// 256-thread block (the register shape this toolchain compiles clean: v3's
// identical per-wave body = 196 VGPR, no spill; 512-thread blocks cap at 128
// VGPR -> 95MB spill, v4-v6) combined with v2's cross-block overlap:
//   - block = 64 token rows; 4 waves = (t: tile-of-pair) x (wn: half); each
//     wave 64 rows x 32 codes, za[2][8] hoisted -> every B fragment read by
//     exactly ONE wave (LDS/CU 20us vs v2's 82us; MFMA 29us now binding).
//   - SINGLE-buffered 64KB pair + 16KB sEn = 80KB -> 2 blocks/CU; partner
//     block's wave on the same SIMD covers this block's staging drain
//     (v2's proven mechanism).
//   - sync per iter: compute -> lgkmcnt(0)+barrier (buffer reads done) ->
//     issue 16 gld16 (pair ct+1, same buffer) -> deferred score VALU hides
//     DMA flight -> vmcnt(0)+barrier. Full drains, no counted-vmcnt ledger.
// Swizzle: granule g of row r at slot g^(r&31) -> conflict-free b128 reads.
__global__ __launch_bounds__(256, 2)
void score_pass(const unsigned char* __restrict__ z8, const unsigned char* __restrict__ e8,
                const float* __restrict__ en32,
                unsigned* __restrict__ rowmin) {
    __shared__ __align__(16) unsigned char sE[65536];    // one 64KB pair buffer
    __shared__ __align__(16) float sEn[NCODE];           // 16KB code norms
    const int tid = threadIdx.x;
    const int row0 = blockIdx.x * 64;    // token rows of this block
    const int wv = tid >> 6, ln = tid & 63;
    const int t  = wv & 1;               // which tile of the pair
    const int wn = wv >> 1;              // code half within the tile
    const int c = ln & 31, h = ln >> 5;

    // ---- stage z tile (64 rows, 32KB) into sE chunks 0..31
#pragma unroll
    for (int s = 0; s < 8; s++) {
        int q = wv * 8 + s;              // 0..31
        int r = 2 * q + h;               // 0..63
        unsigned g = (unsigned)(c ^ (r & 31));
        gld16(z8 + (size_t)(row0 + r) * 512 + g * 16u, sE + q * 1024);
    }
    // ---- stage en32 -> sEn: 16 x 1KB chunks, 4 per wave
#pragma unroll
    for (int s = 0; s < 4; s++) {
        int chunk = wv * 4 + s;
        gld16((const unsigned char*)en32 + chunk * 1024 + (unsigned)(ln * 16),
              (unsigned char*)sEn + chunk * 1024);
    }

    // per-lane pair-stage source offsets (ct-invariant): 16 x 1KB chunks/wave
    unsigned eoff[16];
#pragma unroll
    for (int s = 0; s < 16; s++) {
        int q = wv * 16 + s;             // chunk 0..63 of the 64KB pair
        int rr = 2 * q + h;              // code-row 0..127 within pair
        unsigned g = (unsigned)(c ^ (rr & 31));
        eoff[s] = (unsigned)(rr * 512) + g * 16u;
    }

    asm volatile("s_waitcnt vmcnt(0)" ::: "memory");   // z + en resident
    __builtin_amdgcn_s_barrier();

    // ---- hoist A fragments: rows m*32 + c -> za[2][8] (64 VGPRs)
    const int nrow = (wn * 32 + c) * 512;
    v8i za[2][8];
#pragma unroll
    for (int m = 0; m < 2; m++) {
        const int mbase = (m * 32 + c) * 512;
#pragma unroll
        for (int kt = 0; kt < 8; kt++) {
            int G = kt * 4 + 2 * h;
            union { uint4 u[2]; v8i v; } av;
            av.u[0] = *(const uint4*)(sE + mbase + (((G    ) ^ c) * 16));
            av.u[1] = *(const uint4*)(sE + mbase + (((G + 1) ^ c) * 16));
            za[m][kt] = av.v;
        }
    }
    asm volatile("s_waitcnt lgkmcnt(0)" ::: "memory");
    __builtin_amdgcn_s_barrier();        // all waves done reading z region

    // ---- stage e-pair 0 (overwrites z region)
#pragma unroll
    for (int s = 0; s < 16; s++)
        gld16(e8 + eoff[s], sE + (wv * 16 + s) * 1024);
    asm volatile("s_waitcnt vmcnt(0)" ::: "memory");
    __builtin_amdgcn_s_barrier();        // pair 0 resident

    unsigned runmin[2][16];
#pragma unroll
    for (int m = 0; m < 2; m++)
#pragma unroll
    for (int reg = 0; reg < 16; reg++) runmin[m][reg] = 0xFFFFFFFFu;

    const unsigned char* myb = sE + t * 32768 + nrow;
    const unsigned nbase = (unsigned)(t * 64 + wn * 32 + c);

    for (int ct = 0; ct < 32; ct++) {
        // buffer holds pair ct (guaranteed by the vmcnt(0)+barrier behind us)
        float en = sEn[ct * 128 + nbase];
        float pre = fmaf(en, KSCL, KOFF);
        v16f a0 = (v16f)(0.0f), a1 = (v16f)(0.0f);
        v16f b0 = (v16f)(0.0f), b1 = (v16f)(0.0f);
#pragma unroll
        for (int kt = 0; kt < 8; kt++) {
            int G = kt * 4 + 2 * h;
            union { uint4 u[2]; v8i v; } bv;
            bv.u[0] = *(const uint4*)(myb + (((G    ) ^ c) * 16));
            bv.u[1] = *(const uint4*)(myb + (((G + 1) ^ c) * 16));
            if (kt & 1) {
                a1 = __builtin_amdgcn_mfma_scale_f32_32x32x64_f8f6f4(
                    za[0][kt], bv.v, a1, 0, 0, 0, 0x7F, 0, 0x7F);
                b1 = __builtin_amdgcn_mfma_scale_f32_32x32x64_f8f6f4(
                    za[1][kt], bv.v, b1, 0, 0, 0, 0x7F, 0, 0x7F);
            } else {
                a0 = __builtin_amdgcn_mfma_scale_f32_32x32x64_f8f6f4(
                    za[0][kt], bv.v, a0, 0, 0, 0, 0x7F, 0, 0x7F);
                b0 = __builtin_amdgcn_mfma_scale_f32_32x32x64_f8f6f4(
                    za[1][kt], bv.v, b0, 0, 0, 0, 0x7F, 0, 0x7F);
            }
        }

        asm volatile("s_waitcnt lgkmcnt(0)" ::: "memory"); // my buffer reads done
        __builtin_amdgcn_s_barrier();     // ALL waves' buffer reads done

        if (ct < 31) {                    // stage pair ct+1 into the same buffer
            const unsigned char* ebase = e8 + (size_t)(ct + 1) * 65536;
#pragma unroll
            for (int s = 0; s < 16; s++)
                gld16(ebase + eoff[s], sE + (wv * 16 + s) * 1024);
        }

        // deferred score: VALU hides the staging DMA flight time
        unsigned n = nbase + (unsigned)ct * 128u;
#pragma unroll
        for (int reg = 0; reg < 16; reg++) {
            float s0 = a0[reg] + a1[reg];
            unsigned k0 = (unsigned)fmaf(s0, -64.0f, pre);   // trunc; monotone
            unsigned p0 = (k0 << 12) | n;
            runmin[0][reg] = runmin[0][reg] < p0 ? runmin[0][reg] : p0;
            float s1 = b0[reg] + b1[reg];
            unsigned k1 = (unsigned)fmaf(s1, -64.0f, pre);
            unsigned p1 = (k1 << 12) | n;
            runmin[1][reg] = runmin[1][reg] < p1 ? runmin[1][reg] : p1;
        }

        if (ct < 31) {
            asm volatile("s_waitcnt vmcnt(0)" ::: "memory");  // pair ct+1 resident
            __builtin_amdgcn_s_barrier();
        }
    }

    // ---- cross-lane reduce (32 cols), then cross-wave combine via LDS
    // (sE reusable: the ct=31 lgkm-drain barrier guaranteed all reads done)
    unsigned* tmp = (unsigned*)sE;        // [4 waves][64 rows]
#pragma unroll
    for (int m = 0; m < 2; m++) {
#pragma unroll
        for (int reg = 0; reg < 16; reg++) {
            unsigned v = runmin[m][reg];
#pragma unroll
            for (int off = 1; off < 32; off <<= 1) {
                unsigned o = (unsigned)__shfl_xor((int)v, off);
                v = v < o ? v : o;
            }
            if (c == 0) {
                int r = m * 32 + (reg & 3) + 8 * (reg >> 2) + 4 * h;
                tmp[wv * 64 + r] = v;
            }
        }
    }
    __syncthreads();
    if (tid < 64) {                       // combine the 4 waves' disjoint code sets
        unsigned v0 = tmp[tid], v1 = tmp[64 + tid];
        unsigned v2 = tmp[128 + tid], v3 = tmp[192 + tid];
        unsigned a = v0 < v1 ? v0 : v1, b = v2 < v3 ? v2 : v3;
        rowmin[row0 + tid] = a < b ? a : b;
    }
}

// ---------------- 4. gather + STE output + sse + hist -------------
__global__ void gather_loss(const float* __restrict__ z, const float* __restrict__ emb,
                            const unsigned* __restrict__ rowmin,
                            float* __restrict__ out, double* __restrict__ sse,
                            unsigned* __restrict__ counts) {
    int i = blockIdx.x * blockDim.x + threadIdx.x;   // f4 index, 4194304 total
    float4 zv = ((const float4*)z)[i];
    int row = i >> 7, col = i & 127;
    unsigned code = rowmin[row] & 0xFFFu;
    if (col == 0) atomicAdd(&counts[code], 1u);      // fused histogram: one lane per row
    float4 q = ((const float4*)emb)[code * 128 + col];
    float4 dv = make_float4(q.x - zv.x, q.y - zv.y, q.z - zv.z, q.w - zv.w);
    float4 o  = make_float4(zv.x + dv.x, zv.y + dv.y, zv.z + dv.z, zv.w + dv.w);
    ((float4*)out)[i] = o;
    double loc = (double)dv.x*dv.x + (double)dv.y*dv.y + (double)dv.z*dv.z + (double)dv.w*dv.w;
    for (int off = 32; off; off >>= 1) loc += __shfl_down(loc, off);
    __shared__ double sw[4];
    if ((threadIdx.x & 63) == 0) sw[threadIdx.x >> 6] = loc;
    __syncthreads();
    if (threadIdx.x == 0)
        atomicAdd(&sse[blockIdx.x & 255], sw[0] + sw[1] + sw[2] + sw[3]);  // 256 slots
}

// ---------------- 5. losses + perplexity -------------
__global__ void finalize(const unsigned* __restrict__ counts, const double* __restrict__ sse,
                         float* __restrict__ out) {
    __shared__ double sh[256], sv[256];
    double h = 0.0;
    for (int b = threadIdx.x; b < NCODE; b += 256) {
        double p = (double)counts[b] / (double)NTOK;
        h += p * log(p + 1e-10);
    }
    sh[threadIdx.x] = h;
    sv[threadIdx.x] = sse[threadIdx.x];
    __syncthreads();
    for (int off = 128; off > 0; off >>= 1) {
        if (threadIdx.x < off) {
            sh[threadIdx.x] += sh[threadIdx.x + off];
            sv[threadIdx.x] += sv[threadIdx.x + off];
        }
        __syncthreads();
    }
    if (threadIdx.x == 0) {
        out[NELEM]     = (float)((1.0 + COMMIT) * sv[0] / (double)NELEM);  // vq_loss
        out[NELEM + 1] = (float)exp(-sh[0]);                                // perplexity
    }
}

// ---------------- launch ----------------
extern "C" void kernel_launch(void* const* d_in, const int* in_sizes, int n_in,
                              void* d_out, int out_size, void* d_ws, size_t ws_size,
                              hipStream_t stream) {
    const float* z   = (const float*)d_in[0];
    const float* emb = (const float*)d_in[1];
    float* out = (float*)d_out;
    char* ws = (char*)d_ws;

    unsigned* z8 = (unsigned*)(ws + OFF_Z8);
    unsigned* e8 = (unsigned*)(ws + OFF_E8);
    float*    en32 = (float*)(ws + OFF_EN32);
    unsigned* rowmin = (unsigned*)(ws + OFF_ROWMIN);
    unsigned* counts = (unsigned*)(ws + OFF_COUNTS);
    double*   sse    = (double*)(ws + OFF_SSE);

    conv_kernel<<<(NELEM/16 + (NCODE*DIM)/16 + 255) / 256, 256, 0, stream>>>(
        z, emb, z8, e8, counts, sse);
    enorm_kernel<<<(NCODE * 64) / 256, 256, 0, stream>>>(emb, en32);

    score_pass<<<NTOK / 64, 256, 0, stream>>>((const unsigned char*)z8,
                                              (const unsigned char*)e8, en32, rowmin);

    gather_loss<<<NELEM / 4 / 256, 256, 0, stream>>>(z, emb, rowmin, out, sse, counts);
    finalize<<<1, 256, 0, stream>>>(counts, sse, out);
}

// Round 9
// 273.190 us; speedup vs baseline: 1.1221x; 1.1221x over previous
//
#include <hip/hip_runtime.h>

// ---------------- problem constants ----------------
#define NTOK   32768
#define DIM    512            // bytes per fp8 row too
#define NCODE  4096
#define NELEM  (NTOK*DIM)     // 16777216
#define COMMIT 0.25
#define ESCALE 8192.0f        // 2^13: lifts emb (~2.4e-4) into e4m3 normal range
#define EINV   (1.0f/4096.0f) // 2^-12: score = en - 2*(acc/8192) = en - acc*2^-12
#define KSCL   262144.0f      // 2^18 key quantizer
#define KOFF   65536.0f       // 0.25 * 2^18 (covers |s| <= 0.25 hard bound)
// EINV*KSCL = 64: key = fmaf(en,KSCL,KOFF) - 64*acc (same ordering, fewer ops)

// ---------------- ws layout (bytes) ----------------
#define OFF_Z8      0ULL              // fp8 z: 16777216
#define OFF_E8      16777216ULL       // fp8 e*8192: 2097152
#define OFF_EN32    18874368ULL       // float[4096] = 16384
#define OFF_ROWMIN  18890752ULL       // u32[32768] = 131072 (packed key20|code12)
#define OFF_COUNTS  19021824ULL       // u32[4096] = 16384
#define OFF_SSE     19038208ULL       // double[256] = 2048

typedef int   v8i  __attribute__((ext_vector_type(8)));
typedef float v16f __attribute__((ext_vector_type(16)));

#define GLOBAL_AS __attribute__((address_space(1)))
#define LDS_AS    __attribute__((address_space(3)))

__device__ __forceinline__ void gld16(const void* g, void* l) {
    // async global->LDS, 16B/lane; LDS dest = wave-uniform base + lane*16
    __builtin_amdgcn_global_load_lds((const GLOBAL_AS unsigned int*)g,
                                     (LDS_AS unsigned int*)l, 16, 0, 0);
}

// ---------------- 1. fp32 -> fp8 e4m3 conversion (+ counts/sse init) ----------
__global__ void conv_kernel(const float* __restrict__ z, const float* __restrict__ e,
                            unsigned* __restrict__ z8, unsigned* __restrict__ e8,
                            unsigned* __restrict__ counts, double* __restrict__ sse) {
    const int ZI = NELEM / 16;                 // 1048576 (16 floats -> 16 fp8 per thread)
    const int TI = ZI + (NCODE * DIM) / 16;    // +131072
    int i = blockIdx.x * blockDim.x + threadIdx.x;
    if (i < NCODE) counts[i] = 0u;
    if (i < 256)   sse[i] = 0.0;
    if (i >= TI) return;
    const float4* src; unsigned* dst; int j; float sc;
    if (i < ZI) { src = (const float4*)z; dst = z8; j = i; sc = 1.0f; }
    else        { src = (const float4*)e; dst = e8; j = i - ZI; sc = ESCALE; }
    uint4 o;
#pragma unroll
    for (int q = 0; q < 4; q++) {
        float4 v = src[j * 4 + q];
        int r = 0;
        r = __builtin_amdgcn_cvt_pk_fp8_f32(v.x * sc, v.y * sc, r, false);
        r = __builtin_amdgcn_cvt_pk_fp8_f32(v.z * sc, v.w * sc, r, true);
        (&o.x)[q] = (unsigned)r;
    }
    ((uint4*)dst)[j] = o;
}

// ---------------- 2. ||e_k||^2 (exact f32 via f64 accumulate) ----------------
__global__ void enorm_kernel(const float* __restrict__ emb, float* __restrict__ en32) {
    int gw = (blockIdx.x * blockDim.x + threadIdx.x) >> 6;   // wave id = code
    int lane = threadIdx.x & 63;
    if (gw >= NCODE) return;
    const float4* p = (const float4*)(emb + (size_t)gw * DIM);
    float4 a = p[lane * 2], b = p[lane * 2 + 1];
    double s = (double)a.x*a.x + (double)a.y*a.y + (double)a.z*a.z + (double)a.w*a.w
             + (double)b.x*b.x + (double)b.y*b.y + (double)b.z*b.z + (double)b.w*b.w;
    for (int off = 32; off; off >>= 1) s += __shfl_down(s, off);
    if (lane == 0) en32[gw] = (float)s;
}

// ---------------- 3. persistent-code-loop MX-fp8 score pass (v8) -----------
// v7 structure with the register split decoded and fixed. Empirics across
// v2-v7 on this toolchain: ANY launch-bounds request for >=2 resident groups
// (2nd arg >= 2, or 8-wave blocks) makes the backend split the unified
// 256-reg/wave file into archVGPR 128 + AGPR 128; this body's arch demand
// (~190: za 64, runmin 32, eoff 16, unions+addressing) > 128 -> scratch
// spill (v7: VGPR=128, WRITE 29.8MB, 173us). Only (256,1) ever produced a
// >128 arch allocation (v3: 196, spill-free). So: __launch_bounds__(256,1)
// and let HARDWARE find the occupancy — at ~196 VGPR (<=256) two 4-wave
// blocks co-reside per CU anyway (LDS 80KB x 2 = 160KB fits), giving v2's
// cross-block overlap without asking the compiler for it.
//   - block = 64 token rows; 4 waves = (t: tile-of-pair) x (wn: half); each
//     wave 64 rows x 32 codes, za[2][8] hoisted -> every B fragment read by
//     exactly ONE wave (LDS/CU ~20us; MFMA ~29us binding).
//   - SINGLE-buffered 64KB pair + 16KB sEn = 80KB; partner block's waves on
//     the same SIMDs cover this block's staging drain.
//   - sync per iter: compute -> lgkmcnt(0)+barrier -> issue 16 gld16 (pair
//     ct+1, same buffer) -> deferred score VALU hides DMA flight ->
//     vmcnt(0)+barrier.
// Swizzle: granule g of row r at slot g^(r&31) -> conflict-free b128 reads.
__global__ __launch_bounds__(256, 1)
void score_pass(const unsigned char* __restrict__ z8, const unsigned char* __restrict__ e8,
                const float* __restrict__ en32,
                unsigned* __restrict__ rowmin) {
    __shared__ __align__(16) unsigned char sE[65536];    // one 64KB pair buffer
    __shared__ __align__(16) float sEn[NCODE];           // 16KB code norms
    const int tid = threadIdx.x;
    const int row0 = blockIdx.x * 64;    // token rows of this block
    const int wv = tid >> 6, ln = tid & 63;
    const int t  = wv & 1;               // which tile of the pair
    const int wn = wv >> 1;              // code half within the tile
    const int c = ln & 31, h = ln >> 5;

    // ---- stage z tile (64 rows, 32KB) into sE chunks 0..31
#pragma unroll
    for (int s = 0; s < 8; s++) {
        int q = wv * 8 + s;              // 0..31
        int r = 2 * q + h;               // 0..63
        unsigned g = (unsigned)(c ^ (r & 31));
        gld16(z8 + (size_t)(row0 + r) * 512 + g * 16u, sE + q * 1024);
    }
    // ---- stage en32 -> sEn: 16 x 1KB chunks, 4 per wave
#pragma unroll
    for (int s = 0; s < 4; s++) {
        int chunk = wv * 4 + s;
        gld16((const unsigned char*)en32 + chunk * 1024 + (unsigned)(ln * 16),
              (unsigned char*)sEn + chunk * 1024);
    }

    // per-lane pair-stage source offsets (ct-invariant): 16 x 1KB chunks/wave
    unsigned eoff[16];
#pragma unroll
    for (int s = 0; s < 16; s++) {
        int q = wv * 16 + s;             // chunk 0..63 of the 64KB pair
        int rr = 2 * q + h;              // code-row 0..127 within pair
        unsigned g = (unsigned)(c ^ (rr & 31));
        eoff[s] = (unsigned)(rr * 512) + g * 16u;
    }

    asm volatile("s_waitcnt vmcnt(0)" ::: "memory");   // z + en resident
    __builtin_amdgcn_s_barrier();

    // ---- hoist A fragments: rows m*32 + c -> za[2][8] (64 VGPRs)
    const int nrow = (wn * 32 + c) * 512;
    v8i za[2][8];
#pragma unroll
    for (int m = 0; m < 2; m++) {
        const int mbase = (m * 32 + c) * 512;
#pragma unroll
        for (int kt = 0; kt < 8; kt++) {
            int G = kt * 4 + 2 * h;
            union { uint4 u[2]; v8i v; } av;
            av.u[0] = *(const uint4*)(sE + mbase + (((G    ) ^ c) * 16));
            av.u[1] = *(const uint4*)(sE + mbase + (((G + 1) ^ c) * 16));
            za[m][kt] = av.v;
        }
    }
    asm volatile("s_waitcnt lgkmcnt(0)" ::: "memory");
    __builtin_amdgcn_s_barrier();        // all waves done reading z region

    // ---- stage e-pair 0 (overwrites z region)
#pragma unroll
    for (int s = 0; s < 16; s++)
        gld16(e8 + eoff[s], sE + (wv * 16 + s) * 1024);
    asm volatile("s_waitcnt vmcnt(0)" ::: "memory");
    __builtin_amdgcn_s_barrier();        // pair 0 resident

    unsigned runmin[2][16];
#pragma unroll
    for (int m = 0; m < 2; m++)
#pragma unroll
    for (int reg = 0; reg < 16; reg++) runmin[m][reg] = 0xFFFFFFFFu;

    const unsigned char* myb = sE + t * 32768 + nrow;
    const unsigned nbase = (unsigned)(t * 64 + wn * 32 + c);

    for (int ct = 0; ct < 32; ct++) {
        // buffer holds pair ct (guaranteed by the vmcnt(0)+barrier behind us)
        float en = sEn[ct * 128 + nbase];
        float pre = fmaf(en, KSCL, KOFF);
        v16f a0 = (v16f)(0.0f), a1 = (v16f)(0.0f);
        v16f b0 = (v16f)(0.0f), b1 = (v16f)(0.0f);
#pragma unroll
        for (int kt = 0; kt < 8; kt++) {
            int G = kt * 4 + 2 * h;
            union { uint4 u[2]; v8i v; } bv;
            bv.u[0] = *(const uint4*)(myb + (((G    ) ^ c) * 16));
            bv.u[1] = *(const uint4*)(myb + (((G + 1) ^ c) * 16));
            if (kt & 1) {
                a1 = __builtin_amdgcn_mfma_scale_f32_32x32x64_f8f6f4(
                    za[0][kt], bv.v, a1, 0, 0, 0, 0x7F, 0, 0x7F);
                b1 = __builtin_amdgcn_mfma_scale_f32_32x32x64_f8f6f4(
                    za[1][kt], bv.v, b1, 0, 0, 0, 0x7F, 0, 0x7F);
            } else {
                a0 = __builtin_amdgcn_mfma_scale_f32_32x32x64_f8f6f4(
                    za[0][kt], bv.v, a0, 0, 0, 0, 0x7F, 0, 0x7F);
                b0 = __builtin_amdgcn_mfma_scale_f32_32x32x64_f8f6f4(
                    za[1][kt], bv.v, b0, 0, 0, 0, 0x7F, 0, 0x7F);
            }
        }

        asm volatile("s_waitcnt lgkmcnt(0)" ::: "memory"); // my buffer reads done
        __builtin_amdgcn_s_barrier();     // ALL waves' buffer reads done

        if (ct < 31) {                    // stage pair ct+1 into the same buffer
            const unsigned char* ebase = e8 + (size_t)(ct + 1) * 65536;
#pragma unroll
            for (int s = 0; s < 16; s++)
                gld16(ebase + eoff[s], sE + (wv * 16 + s) * 1024);
        }

        // deferred score: VALU hides the staging DMA flight time
        unsigned n = nbase + (unsigned)ct * 128u;
#pragma unroll
        for (int reg = 0; reg < 16; reg++) {
            float s0 = a0[reg] + a1[reg];
            unsigned k0 = (unsigned)fmaf(s0, -64.0f, pre);   // trunc; monotone
            unsigned p0 = (k0 << 12) | n;
            runmin[0][reg] = runmin[0][reg] < p0 ? runmin[0][reg] : p0;
            float s1 = b0[reg] + b1[reg];
            unsigned k1 = (unsigned)fmaf(s1, -64.0f, pre);
            unsigned p1 = (k1 << 12) | n;
            runmin[1][reg] = runmin[1][reg] < p1 ? runmin[1][reg] : p1;
        }

        if (ct < 31) {
            asm volatile("s_waitcnt vmcnt(0)" ::: "memory");  // pair ct+1 resident
            __builtin_amdgcn_s_barrier();
        }
    }

    // ---- cross-lane reduce (32 cols), then cross-wave combine via LDS
    // (sE reusable: the ct=31 lgkm-drain barrier guaranteed all reads done)
    unsigned* tmp = (unsigned*)sE;        // [4 waves][64 rows]
#pragma unroll
    for (int m = 0; m < 2; m++) {
#pragma unroll
        for (int reg = 0; reg < 16; reg++) {
            unsigned v = runmin[m][reg];
#pragma unroll
            for (int off = 1; off < 32; off <<= 1) {
                unsigned o = (unsigned)__shfl_xor((int)v, off);
                v = v < o ? v : o;
            }
            if (c == 0) {
                int r = m * 32 + (reg & 3) + 8 * (reg >> 2) + 4 * h;
                tmp[wv * 64 + r] = v;
            }
        }
    }
    __syncthreads();
    if (tid < 64) {                       // combine the 4 waves' disjoint code sets
        unsigned v0 = tmp[tid], v1 = tmp[64 + tid];
        unsigned v2 = tmp[128 + tid], v3 = tmp[192 + tid];
        unsigned a = v0 < v1 ? v0 : v1, b = v2 < v3 ? v2 : v3;
        rowmin[row0 + tid] = a < b ? a : b;
    }
}

// ---------------- 4. gather + STE output + sse + hist -------------
__global__ void gather_loss(const float* __restrict__ z, const float* __restrict__ emb,
                            const unsigned* __restrict__ rowmin,
                            float* __restrict__ out, double* __restrict__ sse,
                            unsigned* __restrict__ counts) {
    int i = blockIdx.x * blockDim.x + threadIdx.x;   // f4 index, 4194304 total
    float4 zv = ((const float4*)z)[i];
    int row = i >> 7, col = i & 127;
    unsigned code = rowmin[row] & 0xFFFu;
    if (col == 0) atomicAdd(&counts[code], 1u);      // fused histogram: one lane per row
    float4 q = ((const float4*)emb)[code * 128 + col];
    float4 dv = make_float4(q.x - zv.x, q.y - zv.y, q.z - zv.z, q.w - zv.w);
    float4 o  = make_float4(zv.x + dv.x, zv.y + dv.y, zv.z + dv.z, zv.w + dv.w);
    ((float4*)out)[i] = o;
    double loc = (double)dv.x*dv.x + (double)dv.y*dv.y + (double)dv.z*dv.z + (double)dv.w*dv.w;
    for (int off = 32; off; off >>= 1) loc += __shfl_down(loc, off);
    __shared__ double sw[4];
    if ((threadIdx.x & 63) == 0) sw[threadIdx.x >> 6] = loc;
    __syncthreads();
    if (threadIdx.x == 0)
        atomicAdd(&sse[blockIdx.x & 255], sw[0] + sw[1] + sw[2] + sw[3]);  // 256 slots
}

// ---------------- 5. losses + perplexity -------------
__global__ void finalize(const unsigned* __restrict__ counts, const double* __restrict__ sse,
                         float* __restrict__ out) {
    __shared__ double sh[256], sv[256];
    double h = 0.0;
    for (int b = threadIdx.x; b < NCODE; b += 256) {
        double p = (double)counts[b] / (double)NTOK;
        h += p * log(p + 1e-10);
    }
    sh[threadIdx.x] = h;
    sv[threadIdx.x] = sse[threadIdx.x];
    __syncthreads();
    for (int off = 128; off > 0; off >>= 1) {
        if (threadIdx.x < off) {
            sh[threadIdx.x] += sh[threadIdx.x + off];
            sv[threadIdx.x] += sv[threadIdx.x + off];
        }
        __syncthreads();
    }
    if (threadIdx.x == 0) {
        out[NELEM]     = (float)((1.0 + COMMIT) * sv[0] / (double)NELEM);  // vq_loss
        out[NELEM + 1] = (float)exp(-sh[0]);                                // perplexity
    }
}

// ---------------- launch ----------------
extern "C" void kernel_launch(void* const* d_in, const int* in_sizes, int n_in,
                              void* d_out, int out_size, void* d_ws, size_t ws_size,
                              hipStream_t stream) {
    const float* z   = (const float*)d_in[0];
    const float* emb = (const float*)d_in[1];
    float* out = (float*)d_out;
    char* ws = (char*)d_ws;

    unsigned* z8 = (unsigned*)(ws + OFF_Z8);
    unsigned* e8 = (unsigned*)(ws + OFF_E8);
    float*    en32 = (float*)(ws + OFF_EN32);
    unsigned* rowmin = (unsigned*)(ws + OFF_ROWMIN);
    unsigned* counts = (unsigned*)(ws + OFF_COUNTS);
    double*   sse    = (double*)(ws + OFF_SSE);

    conv_kernel<<<(NELEM/16 + (NCODE*DIM)/16 + 255) / 256, 256, 0, stream>>>(
        z, emb, z8, e8, counts, sse);
    enorm_kernel<<<(NCODE * 64) / 256, 256, 0, stream>>>(emb, en32);

    score_pass<<<NTOK / 64, 256, 0, stream>>>((const unsigned char*)z8,
                                              (const unsigned char*)e8, en32, rowmin);

    gather_loss<<<NELEM / 4 / 256, 256, 0, stream>>>(z, emb, rowmin, out, sse, counts);
    finalize<<<1, 256, 0, stream>>>(counts, sse, out);
}

// Round 10
// 217.145 us; speedup vs baseline: 1.4117x; 1.2581x over previous
//
#include <hip/hip_runtime.h>

// ---------------- problem constants ----------------
#define NTOK   32768
#define DIM    512            // bytes per fp8 row too
#define NCODE  4096
#define NELEM  (NTOK*DIM)     // 16777216
#define COMMIT 0.25
#define ESCALE 8192.0f        // 2^13: lifts emb (~2.4e-4) into e4m3 normal range
#define EINV   (1.0f/4096.0f) // 2^-12: score = en - 2*(acc/8192) = en - acc*2^-12
#define KSCL   262144.0f      // 2^18 key quantizer
#define KOFF   65536.0f       // 0.25 * 2^18 (covers |s| <= 0.25 hard bound)

// ---------------- ws layout (bytes) ----------------
#define OFF_Z8      0ULL              // fp8 z: 16777216
#define OFF_E8      16777216ULL       // fp8 e*8192: 2097152
#define OFF_EN32    18874368ULL       // float[4096] = 16384
#define OFF_ROWMIN  18890752ULL       // (unused in v9)
#define OFF_COUNTS  19021824ULL       // u32[4096] = 16384
#define OFF_SSE     19038208ULL       // double[256] = 2048

typedef int   v8i  __attribute__((ext_vector_type(8)));
typedef float v16f __attribute__((ext_vector_type(16)));

#define GLOBAL_AS __attribute__((address_space(1)))
#define LDS_AS    __attribute__((address_space(3)))

__device__ __forceinline__ void gld16(const void* g, void* l) {
    // async global->LDS, 16B/lane; LDS dest = wave-uniform base + lane*16
    __builtin_amdgcn_global_load_lds((const GLOBAL_AS unsigned int*)g,
                                     (LDS_AS unsigned int*)l, 16, 0, 0);
}

// ---------------- 1. fp32 -> fp8 conversion + FUSED ||e||^2 + inits ---------
// emb-range blocks are uniform (ZI, TI multiples of 256): each emb thread
// handles 16 floats = 1/32 row; 32 consecutive lanes = one row -> 5-step
// shfl_xor double reduction gives the row norm. Replaces enorm_kernel.
__global__ void conv_kernel(const float* __restrict__ z, const float* __restrict__ e,
                            unsigned* __restrict__ z8, unsigned* __restrict__ e8,
                            unsigned* __restrict__ counts, double* __restrict__ sse,
                            float* __restrict__ en32) {
    const int ZI = NELEM / 16;                 // 1048576
    const int TI = ZI + (NCODE * DIM) / 16;    // +131072
    int i = blockIdx.x * blockDim.x + threadIdx.x;
    if (i < NCODE) counts[i] = 0u;
    if (i < 256)   sse[i] = 0.0;
    if (i >= TI) return;
    const bool isEmb = (i >= ZI);              // block-uniform
    const float4* src; unsigned* dst; int j; float sc;
    if (!isEmb) { src = (const float4*)z; dst = z8; j = i; sc = 1.0f; }
    else        { src = (const float4*)e; dst = e8; j = i - ZI; sc = ESCALE; }
    uint4 o;
    double nrm = 0.0;
#pragma unroll
    for (int q = 0; q < 4; q++) {
        float4 v = src[j * 4 + q];
        if (isEmb)
            nrm += (double)v.x*v.x + (double)v.y*v.y + (double)v.z*v.z + (double)v.w*v.w;
        int r = 0;
        r = __builtin_amdgcn_cvt_pk_fp8_f32(v.x * sc, v.y * sc, r, false);
        r = __builtin_amdgcn_cvt_pk_fp8_f32(v.z * sc, v.w * sc, r, true);
        (&o.x)[q] = (unsigned)r;
    }
    ((uint4*)dst)[j] = o;
    if (isEmb) {
        // sum the 32 lanes of this row (offsets <=16 stay within the 32-group)
#pragma unroll
        for (int off = 16; off; off >>= 1) nrm += __shfl_xor(nrm, off);
        if ((j & 31) == 0) en32[j >> 5] = (float)nrm;
    }
}

// ---------------- 2. score pass (v2 loop, proven 78-87us) + FUSED gather ----
// Main loop identical to the round-1/2 verified kernel: 4 waves = (wm row
// half) x (wn code half); z staged once -> za[8] hoisted; e tiles (32KB)
// double-buffered in sB0/sB1 with counted vmcnt(8) (never drained in-loop);
// 80KB LDS -> 2 blocks/CU, partner block hides barrier drains.
// NEW epilogue: the block's 64 argmin codes stay in LDS (no rowmin round
// trip); the same block performs gather + STE output + sse + histogram for
// its 64 token rows. Removes the gather_loss kernel and one launch gap.
__global__ __launch_bounds__(256, 2)
void score_pass(const unsigned char* __restrict__ z8, const unsigned char* __restrict__ e8,
                const float* __restrict__ en32,
                const float* __restrict__ zf32, const float* __restrict__ embf,
                float* __restrict__ out, double* __restrict__ sse,
                unsigned* __restrict__ counts) {
    __shared__ __align__(16) unsigned char sB0[64 * 512];   // e-tile buffer A
    __shared__ __align__(16) unsigned char sB1[64 * 512];   // z staging, then e buffer B
    __shared__ __align__(16) float sEn[NCODE];               // 16KB code norms
    const int tid = threadIdx.x;
    const int row0 = blockIdx.x * 64;    // token rows of this block
    const int wv = tid >> 6, ln = tid & 63;
    const int wm = wv & 1;               // row half  (32 rows)
    const int wn = wv >> 1;              // col half  (32 codes of the 64-code tile)
    const int c = ln & 31, h = ln >> 5;

    // ---- stage z tile into sB1: gld16 #q covers rows {2q, 2q+1}
#pragma unroll
    for (int s = 0; s < 8; s++) {
        int q = wv * 8 + s;
        int r = 2 * q + h;
        unsigned g = (unsigned)((ln & 31) ^ (r & 31));
        gld16(z8 + (size_t)(row0 + r) * 512 + g * 16u, sB1 + q * 1024);
    }
    // ---- stage en32 -> sEn: 16 x 1KB chunks, 4 per wave
#pragma unroll
    for (int s = 0; s < 4; s++) {
        int chunk = wv * 4 + s;
        gld16((const unsigned char*)en32 + chunk * 1024 + (unsigned)(ln * 16),
              (unsigned char*)sEn + chunk * 1024);
    }

    // per-lane e-tile source offsets (ct-invariant)
    unsigned eoff[8];
#pragma unroll
    for (int s = 0; s < 8; s++) {
        int q = wv * 8 + s;
        int r = 2 * q + h;               // row within 64-code tile
        unsigned g = (unsigned)((ln & 31) ^ (r & 31));
        eoff[s] = (unsigned)(r * 512) + g * 16u;
    }

    // pin issue order: z+en (12) strictly BEFORE tile0 (8), so vmcnt(8) below
    // provably means "z and en staged".
    __builtin_amdgcn_sched_barrier(0);

    // ---- stage e-tile 0 into sB0
#pragma unroll
    for (int s = 0; s < 8; s++)
        gld16(e8 + eoff[s], sB0 + (wv * 8 + s) * 1024);

    asm volatile("s_waitcnt vmcnt(8)" ::: "memory");   // z + en resident
    __builtin_amdgcn_s_barrier();

    // ---- hoist this wave's A fragments (32 z rows x K=512) into registers
    const int mrow = (wm * 32 + c) * 512;
    const int nrow = (wn * 32 + c) * 512;
    v8i za[8];
#pragma unroll
    for (int kt = 0; kt < 8; kt++) {
        int G = kt * 4 + 2 * h;
        uint4 x0 = *(const uint4*)(sB1 + mrow + (((G    ) ^ c) * 16));
        uint4 x1 = *(const uint4*)(sB1 + mrow + (((G + 1) ^ c) * 16));
        za[kt] = (v8i){(int)x0.x, (int)x0.y, (int)x0.z, (int)x0.w,
                       (int)x1.x, (int)x1.y, (int)x1.z, (int)x1.w};
    }
    asm volatile("s_waitcnt lgkmcnt(0)" ::: "memory");
    __builtin_amdgcn_s_barrier();        // all waves done with sB1 -> free

    // ---- stage e-tile 1 into sB1
#pragma unroll
    for (int s = 0; s < 8; s++)
        gld16(e8 + 32768 + eoff[s], sB1 + (wv * 8 + s) * 1024);

    unsigned runmin[16];
#pragma unroll
    for (int reg = 0; reg < 16; reg++) runmin[reg] = 0xFFFFFFFFu;

    for (int ct = 0; ct < 64; ct++) {
        // tile ct resident check: the 8 newest in-flight ops are tile ct+1's
        if (ct == 63) asm volatile("s_waitcnt vmcnt(0)" ::: "memory");
        else          asm volatile("s_waitcnt vmcnt(8)" ::: "memory");
        __builtin_amdgcn_s_barrier();

        const unsigned char* sB = (ct & 1) ? sB1 : sB0;
        float en = sEn[ct * 64 + wn * 32 + c];    // this lane's code norm
        v16f acc0 = (v16f)(0.0f), acc1 = (v16f)(0.0f);
#pragma unroll
        for (int kt = 0; kt < 8; kt++) {
            int G = kt * 4 + 2 * h;
            uint4 y0 = *(const uint4*)(sB + nrow + (((G    ) ^ c) * 16));
            uint4 y1 = *(const uint4*)(sB + nrow + (((G + 1) ^ c) * 16));
            v8i b = (v8i){(int)y0.x, (int)y0.y, (int)y0.z, (int)y0.w,
                          (int)y1.x, (int)y1.y, (int)y1.z, (int)y1.w};
            if (kt & 1)
                acc1 = __builtin_amdgcn_mfma_scale_f32_32x32x64_f8f6f4(
                    za[kt], b, acc1, 0, 0, 0, 0x7F, 0, 0x7F);
            else
                acc0 = __builtin_amdgcn_mfma_scale_f32_32x32x64_f8f6f4(
                    za[kt], b, acc0, 0, 0, 0, 0x7F, 0, 0x7F);
        }

        unsigned n = (unsigned)(ct * 64 + wn * 32 + c);
#pragma unroll
        for (int reg = 0; reg < 16; reg++) {
            float s = en - (acc0[reg] + acc1[reg]) * EINV;
            unsigned kq = (unsigned)fmaf(s, KSCL, KOFF);   // trunc; monotone
            unsigned p = (kq << 12) | n;
            runmin[reg] = runmin[reg] < p ? runmin[reg] : p;
        }

        asm volatile("s_waitcnt lgkmcnt(0)" ::: "memory"); // ds reads of buf done
        __builtin_amdgcn_s_barrier();     // all waves done reading buf[ct&1]

        if (ct < 62) {                    // stage tile ct+2 into buf[ct&1]
            unsigned char* sD = (ct & 1) ? sB1 : sB0;
            const unsigned char* ebase = e8 + (size_t)(ct + 2) * 32768;
#pragma unroll
            for (int s = 0; s < 8; s++)
                gld16(ebase + eoff[s], sD + (wv * 8 + s) * 1024);
        }
    }

    // ---- cross-lane reduce (32 cols per half), then cross-wn combine via LDS
    __syncthreads();                      // done with buffers -> reuse as scratch
    unsigned* tmp = (unsigned*)sB0;       // [4 waves][32 rows]
#pragma unroll
    for (int reg = 0; reg < 16; reg++) {
        unsigned v = runmin[reg];
#pragma unroll
        for (int off = 1; off < 32; off <<= 1) {
            unsigned o = (unsigned)__shfl_xor((int)v, off);
            v = v < o ? v : o;
        }
        if (c == 0) {
            int rr = (reg & 3) + 8 * (reg >> 2) + 4 * h;   // row within 32-half
            tmp[(wm * 2 + wn) * 32 + rr] = v;
        }
    }
    __syncthreads();
    unsigned* rmin = (unsigned*)sB1;      // final per-row code, LDS-resident
    if (tid < 64) {                       // row br = tid: combine the two wn halves
        int wmb = tid >> 5, rr = tid & 31;
        unsigned v0 = tmp[(wmb * 2 + 0) * 32 + rr];
        unsigned v1 = tmp[(wmb * 2 + 1) * 32 + rr];
        unsigned best = v0 < v1 ? v0 : v1;
        rmin[tid] = best & 0xFFFu;
        atomicAdd(&counts[best & 0xFFFu], 1u);   // fused histogram
    }
    __syncthreads();

    // ---- fused gather + STE output + sse for this block's 64 rows ----------
    // 64 rows x 128 float4 = 8192 float4; 32 per thread; 128-thread groups
    // cover one row -> fully coalesced z/out, per-row-uniform emb gather.
    const float4* zf = (const float4*)(zf32 + (size_t)row0 * 512);
    float4*       of = (float4*)(out + (size_t)row0 * 512);
    const float4* ef = (const float4*)embf;
    double loc = 0.0;
#pragma unroll 4
    for (int it = 0; it < 32; it++) {
        int idx = tid + it * 256;
        int row = idx >> 7, col = idx & 127;
        unsigned code = rmin[row];
        float4 zv = zf[idx];
        float4 q  = ef[code * 128 + col];
        float dx = q.x - zv.x, dy = q.y - zv.y, dz = q.z - zv.z, dw = q.w - zv.w;
        of[idx] = make_float4(zv.x + dx, zv.y + dy, zv.z + dz, zv.w + dw);
        loc += (double)dx*dx + (double)dy*dy + (double)dz*dz + (double)dw*dw;
    }
    for (int off = 32; off; off >>= 1) loc += __shfl_down(loc, off);
    double* sw = (double*)sEn;            // sEn free -> double scratch
    if (ln == 0) sw[wv] = loc;
    __syncthreads();
    if (tid == 0)
        atomicAdd(&sse[blockIdx.x & 255], sw[0] + sw[1] + sw[2] + sw[3]);
}

// ---------------- 3. losses + perplexity -------------
__global__ void finalize(const unsigned* __restrict__ counts, const double* __restrict__ sse,
                         float* __restrict__ out) {
    __shared__ double sh[256], sv[256];
    double h = 0.0;
    for (int b = threadIdx.x; b < NCODE; b += 256) {
        double p = (double)counts[b] / (double)NTOK;
        h += p * log(p + 1e-10);
    }
    sh[threadIdx.x] = h;
    sv[threadIdx.x] = sse[threadIdx.x];
    __syncthreads();
    for (int off = 128; off > 0; off >>= 1) {
        if (threadIdx.x < off) {
            sh[threadIdx.x] += sh[threadIdx.x + off];
            sv[threadIdx.x] += sv[threadIdx.x + off];
        }
        __syncthreads();
    }
    if (threadIdx.x == 0) {
        out[NELEM]     = (float)((1.0 + COMMIT) * sv[0] / (double)NELEM);  // vq_loss
        out[NELEM + 1] = (float)exp(-sh[0]);                                // perplexity
    }
}

// ---------------- launch ----------------
extern "C" void kernel_launch(void* const* d_in, const int* in_sizes, int n_in,
                              void* d_out, int out_size, void* d_ws, size_t ws_size,
                              hipStream_t stream) {
    const float* z   = (const float*)d_in[0];
    const float* emb = (const float*)d_in[1];
    float* out = (float*)d_out;
    char* ws = (char*)d_ws;

    unsigned* z8 = (unsigned*)(ws + OFF_Z8);
    unsigned* e8 = (unsigned*)(ws + OFF_E8);
    float*    en32 = (float*)(ws + OFF_EN32);
    unsigned* counts = (unsigned*)(ws + OFF_COUNTS);
    double*   sse    = (double*)(ws + OFF_SSE);

    conv_kernel<<<(NELEM/16 + (NCODE*DIM)/16 + 255) / 256, 256, 0, stream>>>(
        z, emb, z8, e8, counts, sse, en32);

    score_pass<<<NTOK / 64, 256, 0, stream>>>((const unsigned char*)z8,
                                              (const unsigned char*)e8, en32,
                                              z, emb, out, sse, counts);

    finalize<<<1, 256, 0, stream>>>(counts, sse, out);
}

// Round 11
// 212.677 us; speedup vs baseline: 1.4413x; 1.0210x over previous
//
#include <hip/hip_runtime.h>

// ---------------- problem constants ----------------
#define NTOK   32768
#define DIM    512            // bytes per fp8 row too
#define NCODE  4096
#define NELEM  (NTOK*DIM)     // 16777216
#define COMMIT 0.25
#define ESCALE 8192.0f        // 2^13: lifts emb (~2.4e-4) into e4m3 normal range
#define EINV   (1.0f/4096.0f) // 2^-12: score = en - 2*(acc/8192) = en - acc*2^-12
#define KSCL   262144.0f      // 2^18 key quantizer
#define KOFF   65536.0f       // 0.25 * 2^18 (covers |s| <= 0.25 hard bound)

// ---------------- ws layout (bytes) ----------------
#define OFF_E8      16777216ULL       // fp8 e*8192: 2097152
#define OFF_EN32    18874368ULL       // float[4096] = 16384
#define OFF_COUNTS  19021824ULL       // u32[4096] = 16384
#define OFF_SSE     19038208ULL       // double[256] = 2048

typedef int   v8i  __attribute__((ext_vector_type(8)));
typedef float v16f __attribute__((ext_vector_type(16)));

#define GLOBAL_AS __attribute__((address_space(1)))
#define LDS_AS    __attribute__((address_space(3)))

__device__ __forceinline__ void gld16(const void* g, void* l) {
    // async global->LDS, 16B/lane; LDS dest = wave-uniform base + lane*16
    __builtin_amdgcn_global_load_lds((const GLOBAL_AS unsigned int*)g,
                                     (LDS_AS unsigned int*)l, 16, 0, 0);
}

// ---------------- 1. emb prep: fp8 conversion + ||e||^2 + inits -------------
// z is no longer pre-converted (score_pass converts its own 64 rows in the
// prologue) -> this kernel shrinks to the 8MB emb leg (~4us).
__global__ void prep_kernel(const float* __restrict__ e,
                            unsigned* __restrict__ e8,
                            unsigned* __restrict__ counts, double* __restrict__ sse,
                            float* __restrict__ en32) {
    int i = blockIdx.x * blockDim.x + threadIdx.x;     // 131072 threads
    if (i < NCODE) counts[i] = 0u;
    if (i < 256)   sse[i] = 0.0;
    const float4* src = (const float4*)e;
    uint4 o;
    double nrm = 0.0;
#pragma unroll
    for (int q = 0; q < 4; q++) {
        float4 v = src[i * 4 + q];
        nrm += (double)v.x*v.x + (double)v.y*v.y + (double)v.z*v.z + (double)v.w*v.w;
        int r = 0;
        r = __builtin_amdgcn_cvt_pk_fp8_f32(v.x * ESCALE, v.y * ESCALE, r, false);
        r = __builtin_amdgcn_cvt_pk_fp8_f32(v.z * ESCALE, v.w * ESCALE, r, true);
        (&o.x)[q] = (unsigned)r;
    }
    ((uint4*)e8)[i] = o;
    // 32 consecutive lanes cover one emb row (512 floats) -> shfl reduction
#pragma unroll
    for (int off = 16; off; off >>= 1) nrm += __shfl_xor(nrm, off);
    if ((i & 31) == 0) en32[i >> 5] = (float)nrm;
}

// ---------------- 2. score pass: fused z-convert + matmul + gather ----------
// v9 (217us total, best) with conv's z leg folded into the prologue: each
// block reads its 64 z rows as fp32 (128KB coalesced), converts to fp8 in
// register (identical cvt_pk bits to the old conv path) and ds_writes them
// into sB1 with the granule swizzle. Kills the z8 HBM round-trip (write 16MB
// + read 16MB) and the ~20us serial conv z-leg.
// Prologue sync: en/tile-0 gld16 issued, then ONE __syncthreads full drain
// (replaces the sched_barrier + counted-vmcnt prologue). Main-loop ledger
// unchanged from v9: at ct entry 8 outstanding = tile ct+1; vmcnt(0) only at
// ct=63. Epilogue (gather + STE + sse + hist) unchanged from v9 (verified).
__global__ __launch_bounds__(256, 2)
void score_pass(const unsigned char* __restrict__ e8,
                const float* __restrict__ en32,
                const float* __restrict__ zf32, const float* __restrict__ embf,
                float* __restrict__ out, double* __restrict__ sse,
                unsigned* __restrict__ counts) {
    __shared__ __align__(16) unsigned char sB0[64 * 512];   // e-tile buffer A
    __shared__ __align__(16) unsigned char sB1[64 * 512];   // z fp8, then e buffer B
    __shared__ __align__(16) float sEn[NCODE];               // 16KB code norms
    const int tid = threadIdx.x;
    const int row0 = blockIdx.x * 64;    // token rows of this block
    const int wv = tid >> 6, ln = tid & 63;
    const int wm = wv & 1;               // row half  (32 rows)
    const int wn = wv >> 1;              // col half  (32 codes of the 64-code tile)
    const int c = ln & 31, h = ln >> 5;

    // ---- stage en32 -> sEn (async DMA, drained by the __syncthreads below)
#pragma unroll
    for (int s = 0; s < 4; s++) {
        int chunk = wv * 4 + s;
        gld16((const unsigned char*)en32 + chunk * 1024 + (unsigned)(ln * 16),
              (unsigned char*)sEn + chunk * 1024);
    }

    // per-lane e-tile source offsets (ct-invariant)
    unsigned eoff[8];
#pragma unroll
    for (int s = 0; s < 8; s++) {
        int q = wv * 8 + s;
        int r = 2 * q + h;               // row within 64-code tile
        unsigned g = (unsigned)((ln & 31) ^ (r & 31));
        eoff[s] = (unsigned)(r * 512) + g * 16u;
    }
    // ---- stage e-tile 0 into sB0 (async DMA)
#pragma unroll
    for (int s = 0; s < 8; s++)
        gld16(e8 + eoff[s], sB0 + (wv * 8 + s) * 1024);

    // ---- convert this block's 64 z rows fp32 -> fp8 into sB1 (swizzled)
    // granule gi = r*32+g covers row r floats [g*16,(g+1)*16) = zsrc[4*gi+q];
    // dest slot = g ^ (r&31). Consecutive tid -> consecutive g: coalesced.
    {
        const float4* zsrc = (const float4*)(zf32 + (size_t)row0 * 512);
#pragma unroll
        for (int s = 0; s < 8; s++) {
            int gi = tid + s * 256;      // 0..2047
            int r = gi >> 5, g = gi & 31;
            uint4 o;
#pragma unroll
            for (int q = 0; q < 4; q++) {
                float4 v = zsrc[4 * gi + q];
                int rr = 0;
                rr = __builtin_amdgcn_cvt_pk_fp8_f32(v.x, v.y, rr, false);
                rr = __builtin_amdgcn_cvt_pk_fp8_f32(v.z, v.w, rr, true);
                (&o.x)[q] = (unsigned)rr;
            }
            *(uint4*)(sB1 + r * 512 + ((g ^ (r & 31)) << 4)) = o;
        }
    }
    __syncthreads();                     // full drain: z conv + en + tile0 resident

    // ---- hoist this wave's A fragments (32 z rows x K=512) into registers
    const int mrow = (wm * 32 + c) * 512;
    const int nrow = (wn * 32 + c) * 512;
    v8i za[8];
#pragma unroll
    for (int kt = 0; kt < 8; kt++) {
        int G = kt * 4 + 2 * h;
        uint4 x0 = *(const uint4*)(sB1 + mrow + (((G    ) ^ c) * 16));
        uint4 x1 = *(const uint4*)(sB1 + mrow + (((G + 1) ^ c) * 16));
        za[kt] = (v8i){(int)x0.x, (int)x0.y, (int)x0.z, (int)x0.w,
                       (int)x1.x, (int)x1.y, (int)x1.z, (int)x1.w};
    }
    asm volatile("s_waitcnt lgkmcnt(0)" ::: "memory");
    __builtin_amdgcn_s_barrier();        // all waves done with sB1 -> free

    // ---- stage e-tile 1 into sB1
#pragma unroll
    for (int s = 0; s < 8; s++)
        gld16(e8 + 32768 + eoff[s], sB1 + (wv * 8 + s) * 1024);

    unsigned runmin[16];
#pragma unroll
    for (int reg = 0; reg < 16; reg++) runmin[reg] = 0xFFFFFFFFu;

    for (int ct = 0; ct < 64; ct++) {
        // tile ct resident check: the 8 newest in-flight ops are tile ct+1's
        if (ct == 63) asm volatile("s_waitcnt vmcnt(0)" ::: "memory");
        else          asm volatile("s_waitcnt vmcnt(8)" ::: "memory");
        __builtin_amdgcn_s_barrier();

        const unsigned char* sB = (ct & 1) ? sB1 : sB0;
        float en = sEn[ct * 64 + wn * 32 + c];    // this lane's code norm
        v16f acc0 = (v16f)(0.0f), acc1 = (v16f)(0.0f);
#pragma unroll
        for (int kt = 0; kt < 8; kt++) {
            int G = kt * 4 + 2 * h;
            uint4 y0 = *(const uint4*)(sB + nrow + (((G    ) ^ c) * 16));
            uint4 y1 = *(const uint4*)(sB + nrow + (((G + 1) ^ c) * 16));
            v8i b = (v8i){(int)y0.x, (int)y0.y, (int)y0.z, (int)y0.w,
                          (int)y1.x, (int)y1.y, (int)y1.z, (int)y1.w};
            if (kt & 1)
                acc1 = __builtin_amdgcn_mfma_scale_f32_32x32x64_f8f6f4(
                    za[kt], b, acc1, 0, 0, 0, 0x7F, 0, 0x7F);
            else
                acc0 = __builtin_amdgcn_mfma_scale_f32_32x32x64_f8f6f4(
                    za[kt], b, acc0, 0, 0, 0, 0x7F, 0, 0x7F);
        }

        unsigned n = (unsigned)(ct * 64 + wn * 32 + c);
#pragma unroll
        for (int reg = 0; reg < 16; reg++) {
            float s = en - (acc0[reg] + acc1[reg]) * EINV;
            unsigned kq = (unsigned)fmaf(s, KSCL, KOFF);   // trunc; monotone
            unsigned p = (kq << 12) | n;
            runmin[reg] = runmin[reg] < p ? runmin[reg] : p;
        }

        asm volatile("s_waitcnt lgkmcnt(0)" ::: "memory"); // ds reads of buf done
        __builtin_amdgcn_s_barrier();     // all waves done reading buf[ct&1]

        if (ct < 62) {                    // stage tile ct+2 into buf[ct&1]
            unsigned char* sD = (ct & 1) ? sB1 : sB0;
            const unsigned char* ebase = e8 + (size_t)(ct + 2) * 32768;
#pragma unroll
            for (int s = 0; s < 8; s++)
                gld16(ebase + eoff[s], sD + (wv * 8 + s) * 1024);
        }
    }

    // ---- cross-lane reduce (32 cols per half), then cross-wn combine via LDS
    __syncthreads();                      // done with buffers -> reuse as scratch
    unsigned* tmp = (unsigned*)sB0;       // [4 waves][32 rows]
#pragma unroll
    for (int reg = 0; reg < 16; reg++) {
        unsigned v = runmin[reg];
#pragma unroll
        for (int off = 1; off < 32; off <<= 1) {
            unsigned o = (unsigned)__shfl_xor((int)v, off);
            v = v < o ? v : o;
        }
        if (c == 0) {
            int rr = (reg & 3) + 8 * (reg >> 2) + 4 * h;   // row within 32-half
            tmp[(wm * 2 + wn) * 32 + rr] = v;
        }
    }
    __syncthreads();
    unsigned* rmin = (unsigned*)sB1;      // final per-row code, LDS-resident
    if (tid < 64) {                       // row br = tid: combine the two wn halves
        int wmb = tid >> 5, rr = tid & 31;
        unsigned v0 = tmp[(wmb * 2 + 0) * 32 + rr];
        unsigned v1 = tmp[(wmb * 2 + 1) * 32 + rr];
        unsigned best = v0 < v1 ? v0 : v1;
        rmin[tid] = best & 0xFFFu;
        atomicAdd(&counts[best & 0xFFFu], 1u);   // fused histogram
    }
    __syncthreads();

    // ---- fused gather + STE output + sse for this block's 64 rows ----------
    const float4* zf = (const float4*)(zf32 + (size_t)row0 * 512);
    float4*       of = (float4*)(out + (size_t)row0 * 512);
    const float4* ef = (const float4*)embf;
    double loc = 0.0;
#pragma unroll 4
    for (int it = 0; it < 32; it++) {
        int idx = tid + it * 256;
        int row = idx >> 7, col = idx & 127;
        unsigned code = rmin[row];
        float4 zv = zf[idx];
        float4 q  = ef[code * 128 + col];
        float dx = q.x - zv.x, dy = q.y - zv.y, dz = q.z - zv.z, dw = q.w - zv.w;
        of[idx] = make_float4(zv.x + dx, zv.y + dy, zv.z + dz, zv.w + dw);
        loc += (double)dx*dx + (double)dy*dy + (double)dz*dz + (double)dw*dw;
    }
    for (int off = 32; off; off >>= 1) loc += __shfl_down(loc, off);
    double* sw = (double*)sEn;            // sEn free -> double scratch
    if (ln == 0) sw[wv] = loc;
    __syncthreads();
    if (tid == 0)
        atomicAdd(&sse[blockIdx.x & 255], sw[0] + sw[1] + sw[2] + sw[3]);
}

// ---------------- 3. losses + perplexity -------------
__global__ void finalize(const unsigned* __restrict__ counts, const double* __restrict__ sse,
                         float* __restrict__ out) {
    __shared__ double sh[256], sv[256];
    double h = 0.0;
    for (int b = threadIdx.x; b < NCODE; b += 256) {
        double p = (double)counts[b] / (double)NTOK;
        h += p * log(p + 1e-10);
    }
    sh[threadIdx.x] = h;
    sv[threadIdx.x] = sse[threadIdx.x];
    __syncthreads();
    for (int off = 128; off > 0; off >>= 1) {
        if (threadIdx.x < off) {
            sh[threadIdx.x] += sh[threadIdx.x + off];
            sv[threadIdx.x] += sv[threadIdx.x + off];
        }
        __syncthreads();
    }
    if (threadIdx.x == 0) {
        out[NELEM]     = (float)((1.0 + COMMIT) * sv[0] / (double)NELEM);  // vq_loss
        out[NELEM + 1] = (float)exp(-sh[0]);                                // perplexity
    }
}

// ---------------- launch ----------------
extern "C" void kernel_launch(void* const* d_in, const int* in_sizes, int n_in,
                              void* d_out, int out_size, void* d_ws, size_t ws_size,
                              hipStream_t stream) {
    const float* z   = (const float*)d_in[0];
    const float* emb = (const float*)d_in[1];
    float* out = (float*)d_out;
    char* ws = (char*)d_ws;

    unsigned* e8 = (unsigned*)(ws + OFF_E8);
    float*    en32 = (float*)(ws + OFF_EN32);
    unsigned* counts = (unsigned*)(ws + OFF_COUNTS);
    double*   sse    = (double*)(ws + OFF_SSE);

    prep_kernel<<<(NCODE * DIM / 16) / 256, 256, 0, stream>>>(
        emb, e8, counts, sse, en32);

    score_pass<<<NTOK / 64, 256, 0, stream>>>((const unsigned char*)e8, en32,
                                              z, emb, out, sse, counts);

    finalize<<<1, 256, 0, stream>>>(counts, sse, out);
}